// Round 4
// baseline (2684.373 us; speedup 1.0000x reference)
//
#include <hip/hip_runtime.h>

#define N_NODES 65536
#define N_EDGES 262144

typedef unsigned short u16;
typedef unsigned char u8;
typedef float f32x4 __attribute__((ext_vector_type(4)));
typedef _Float16 h2 __attribute__((ext_vector_type(2)));
typedef _Float16 v8h __attribute__((ext_vector_type(8)));

__device__ __forceinline__ u16 f2h(float f) {
  return __builtin_bit_cast(u16, (_Float16)f);
}
// 8-bit e5m2 == top byte of fp16 with RNE rounding.
__device__ __forceinline__ u8 f2e5m2(float f) {
  _Float16 h = (_Float16)f;
  u16 hb = __builtin_bit_cast(u16, h);
  hb = (u16)(hb + 0x7F + ((hb >> 8) & 1));
  return (u8)(hb >> 8);
}
// decode dword = 4 e5m2 bytes -> 4 floats (node_gather)
__device__ __forceinline__ void dec4(unsigned d, float* o) {
  o[0] = (float)__builtin_bit_cast(_Float16, (u16)((d << 8) & 0xFF00u));
  o[1] = (float)__builtin_bit_cast(_Float16, (u16)(d & 0xFF00u));
  o[2] = (float)__builtin_bit_cast(_Float16, (u16)((d >> 8) & 0xFF00u));
  o[3] = (float)__builtin_bit_cast(_Float16, (u16)((d >> 16) & 0xFF00u));
}
// e5m2 bytes (b0,b1) of dword -> fp16 pair via one v_perm: [0,b0,0,b1]
__device__ __forceinline__ h2 e5lo(unsigned d) {
  return __builtin_bit_cast(h2, __builtin_amdgcn_perm(d, 0u, 0x05000400u));
}
__device__ __forceinline__ h2 e5hi(unsigned d) {
  return __builtin_bit_cast(h2, __builtin_amdgcn_perm(d, 0u, 0x07000600u));
}
// sigmoid-form gelu: x - x/(1+exp(1.702x)); ~6 VALU ops, |err|<~0.02
__device__ __forceinline__ float gelu_s(float x) {
  float e = __expf(1.702f * x);
  return x - __fdividef(x, e + 1.0f);
}
// tanh-form gelu (more accurate, used in node f-MLP epilogue)
__device__ __forceinline__ float gelu_f(float x) {
  float y = 1.5957691216057308f * (x + 0.044715f * x * x * x);
  float e = __expf(y);
  return x - __fdividef(x, e + 1.0f);
}

// ---------------- LayerNorm -> fp16 (one wave per 256-wide row) ----------------
__global__ __launch_bounds__(256) void ln_kernel(const float* __restrict__ x,
                                                 const float* __restrict__ g,
                                                 const float* __restrict__ b,
                                                 u16* __restrict__ out) {
  int row = blockIdx.x * 4 + (threadIdx.x >> 6);
  int lane = threadIdx.x & 63;
  float4 v = ((const float4*)(x + (size_t)row * 256))[lane];
  float s = v.x + v.y + v.z + v.w;
  float s2 = v.x * v.x + v.y * v.y + v.z * v.z + v.w * v.w;
#pragma unroll
  for (int off = 1; off < 64; off <<= 1) {
    s += __shfl_xor(s, off, 64);
    s2 += __shfl_xor(s2, off, 64);
  }
  float mean = s * (1.0f / 256.0f);
  float var = s2 * (1.0f / 256.0f) - mean * mean;
  float rs = rsqrtf(var + 1e-5f);
  float4 gv = ((const float4*)g)[lane];
  float4 bv = ((const float4*)b)[lane];
  ushort4 o;
  o.x = f2h((v.x - mean) * rs * gv.x + bv.x);
  o.y = f2h((v.y - mean) * rs * gv.y + bv.y);
  o.z = f2h((v.z - mean) * rs * gv.z + bv.z);
  o.w = f2h((v.w - mean) * rs * gv.w + bv.w);
  *(ushort4*)(out + (size_t)row * 256 + lane * 4) = o;
}

// ---------------- generic fp16 GEMM: C[m,n] = sum_k A[m,k] * BT[n,k] ----------------
template <typename Epi>
__global__ __launch_bounds__(256) void gemm_bt(const u16* __restrict__ A,
                                               const u16* __restrict__ BT,
                                               int K, Epi epi) {
  __shared__ __align__(16) u16 sA[128 * 48];
  __shared__ __align__(16) u16 sB[128 * 48];
  const int tm = blockIdx.x * 128, tn = blockIdx.y * 128;
  const int t = threadIdx.x;
  const int wave = t >> 6, lane = t & 63;
  const int lrow = lane & 15, quad = lane >> 4;
  const int wrow = (wave & 1) * 64, wcol = (wave >> 1) * 64;
  const int r = t >> 2, c = (t & 3) << 3;
  f32x4 acc[4][4];
  const f32x4 z = {0.f, 0.f, 0.f, 0.f};
#pragma unroll
  for (int i = 0; i < 4; ++i)
#pragma unroll
    for (int j = 0; j < 4; ++j) acc[i][j] = z;
  for (int k0 = 0; k0 < K; k0 += 32) {
    *(uint4*)&sA[r * 48 + c] = *(const uint4*)&A[(size_t)(tm + r) * K + k0 + c];
    *(uint4*)&sA[(r + 64) * 48 + c] = *(const uint4*)&A[(size_t)(tm + r + 64) * K + k0 + c];
    *(uint4*)&sB[r * 48 + c] = *(const uint4*)&BT[(size_t)(tn + r) * K + k0 + c];
    *(uint4*)&sB[(r + 64) * 48 + c] = *(const uint4*)&BT[(size_t)(tn + r + 64) * K + k0 + c];
    __syncthreads();
    v8h af[4], bfv[4];
#pragma unroll
    for (int i = 0; i < 4; ++i) af[i] = *(const v8h*)&sA[(wrow + i * 16 + lrow) * 48 + quad * 8];
#pragma unroll
    for (int j = 0; j < 4; ++j) bfv[j] = *(const v8h*)&sB[(wcol + j * 16 + lrow) * 48 + quad * 8];
#pragma unroll
    for (int i = 0; i < 4; ++i)
#pragma unroll
      for (int j = 0; j < 4; ++j)
        acc[i][j] = __builtin_amdgcn_mfma_f32_16x16x32_f16(af[i], bfv[j], acc[i][j], 0, 0, 0);
    __syncthreads();
  }
#pragma unroll
  for (int i = 0; i < 4; ++i)
#pragma unroll
    for (int j = 0; j < 4; ++j)
#pragma unroll
      for (int rg = 0; rg < 4; ++rg)
        epi(tm + wrow + i * 16 + quad * 4 + rg, tn + wcol + j * 16 + lrow, acc[i][j][rg]);
}

struct EpiAB {
  u8* out;
  const float* b1cat;
  __device__ void operator()(int m, int n, float v) const {
    if (n < 1536) v += b1cat[n];  // fold b1 into src half
    out[(size_t)m * 3072 + n] = f2e5m2(v);
  }
};
struct EpiX2 {
  float* x2;
  const float* x1;
  const float* rb;
  __device__ void operator()(int m, int n, float v) const {
    x2[(size_t)m * 256 + n] = v + rb[n] + x1[(size_t)m * 256 + n];
  }
};
struct EpiHf {
  u16* hf;
  const float* b1;
  __device__ void operator()(int m, int n, float v) const {
    hf[(size_t)m * 512 + n] = f2h(gelu_f(v + b1[n]));
  }
};
struct EpiOut {
  float* out;
  const float* b2;
  const float* x2;
  __device__ void operator()(int m, int n, float v) const {
    out[(size_t)m * 256 + n] = v + b2[n] + x2[(size_t)m * 256 + n];
  }
};

// ---------------- weight repacks (fp32 -> fp16, B-transposed) ----------------
__global__ void prep_w1catT(u16* __restrict__ out, const float* __restrict__ qW1,
                            const float* __restrict__ kW1, const float* __restrict__ vW1) {
  int cIdx = blockIdx.x;
  int rIdx = threadIdx.x;
  int sec = cIdx >> 9;
  int h = cIdx & 511;
  int mlp = sec % 3;
  const float* W1 = (mlp == 0) ? qW1 : (mlp == 1) ? kW1 : vW1;
  int rowoff = (sec < 3) ? 0 : 256;
  out[(size_t)cIdx * 256 + rIdx] = f2h(W1[(size_t)(rowoff + rIdx) * 512 + h]);
}
__global__ void prep_w2T(u16* __restrict__ out, const float* __restrict__ qW2,
                         const float* __restrict__ kW2, const float* __restrict__ vW2) {
  int row = blockIdx.x;
  int m = row >> 8, n = row & 255;
  const float* W2 = (m == 0) ? qW2 : (m == 1) ? kW2 : vW2;
  for (int k = threadIdx.x; k < 512; k += 256)
    out[(size_t)row * 512 + k] = f2h(W2[(size_t)k * 256 + n]);
}
__global__ void transpose_cast(u16* __restrict__ out, const float* __restrict__ in, int K, int Nn) {
  int n = blockIdx.x;
  for (int k = threadIdx.x; k < K; k += blockDim.x)
    out[(size_t)n * K + k] = f2h(in[(size_t)k * Nn + n]);
}
// w1e16[m][r][512] fp16 = W1_m rows 512..514 (edge-attr rows)
__global__ void prep_w1e16(u16* __restrict__ out, const float* __restrict__ qW1,
                           const float* __restrict__ kW1, const float* __restrict__ vW1) {
  int b = blockIdx.x;  // m*3 + r
  int m = b / 3, r = b % 3;
  const float* W1 = (m == 0) ? qW1 : (m == 1) ? kW1 : vW1;
  out[(size_t)b * 512 + threadIdx.x] = f2h(W1[(size_t)(512 + r) * 512 + threadIdx.x]);
}
__global__ void prep_b1cat(float* __restrict__ out, const float* __restrict__ qb1,
                           const float* __restrict__ kb1, const float* __restrict__ vb1) {
  int idx = blockIdx.x * 256 + threadIdx.x;  // 1536
  const float* b = (idx < 512) ? qb1 : (idx < 1024) ? kb1 : vb1;
  out[idx] = b[idx & 511];
}

// ---------------- CSR build: histogram -> scan -> id scatter ----------------
__global__ __launch_bounds__(256) void hist_kernel(const int* __restrict__ dst,
                                                   unsigned* __restrict__ cnt) {
  int e = blockIdx.x * 256 + threadIdx.x;
  atomicAdd(&cnt[dst[e]], 1u);
}
__global__ __launch_bounds__(1024) void scan_kernel(const unsigned* __restrict__ cnt,
                                                    unsigned* __restrict__ off,
                                                    unsigned* __restrict__ woff) {
  __shared__ unsigned s_part[1024];
  int t = threadIdx.x;
  unsigned local[64];
  unsigned run = 0;
  const uint4* cp = (const uint4*)(cnt + t * 64);
#pragma unroll
  for (int j = 0; j < 16; ++j) {
    uint4 v = cp[j];
    local[j * 4 + 0] = v.x; local[j * 4 + 1] = v.y;
    local[j * 4 + 2] = v.z; local[j * 4 + 3] = v.w;
  }
#pragma unroll
  for (int j = 0; j < 64; ++j) { unsigned c = local[j]; local[j] = run; run += c; }
  s_part[t] = run;
  __syncthreads();
  for (int d = 1; d < 1024; d <<= 1) {
    unsigned v = (t >= d) ? s_part[t - d] : 0u;
    __syncthreads();
    s_part[t] += v;
    __syncthreads();
  }
  unsigned base = (t == 0) ? 0u : s_part[t - 1];
  for (int j = 0; j < 64; ++j) {
    unsigned o = base + local[j];
    off[t * 64 + j] = o;
    woff[t * 64 + j] = o;
  }
}
__global__ __launch_bounds__(256) void scatter_ids(const int* __restrict__ dst,
                                                   unsigned* __restrict__ woff,
                                                   unsigned* __restrict__ eid) {
  int e = blockIdx.x * 256 + threadIdx.x;
  unsigned pos = atomicAdd(&woff[dst[e]], 1u);
  eid[pos] = (unsigned)e;
}

// ---------------- s-MLP bias precompute: sbias[e][h] ----------------
__global__ __launch_bounds__(256) void sbias_kernel(const float* __restrict__ eattr,
                                                    const float* __restrict__ sW1,
                                                    const float* __restrict__ sb1,
                                                    const float* __restrict__ sW2,
                                                    const float* __restrict__ sb2,
                                                    float* __restrict__ sbias) {
  int idx = blockIdx.x * 256 + threadIdx.x;  // e*8 + h
  int e = idx >> 3, h = idx & 7;
  const float* ea = eattr + (size_t)e * 7;
  float a0 = ea[3], a1 = ea[4], a2 = ea[5], a3 = ea[6];
  float acc = sb2[h];
#pragma unroll 4
  for (int j = 0; j < 64; ++j) {
    float zz = fmaxf(a0 * sW1[j] + a1 * sW1[64 + j] + a2 * sW1[128 + j] + a3 * sW1[192 + j] + sb1[j], 0.f);
    acc += zz * sW2[j * 8 + h];
  }
  sbias[idx] = acc;
}

// ---------------- fused edge kernel: 16 edges/block, ~30.6KB LDS, 4 blocks/CU ----------------
__global__ __launch_bounds__(256, 4) void edge_kernel(
    const int* __restrict__ eidx, const float* __restrict__ eattr,
    const u8* __restrict__ AB, const u16* __restrict__ W2T, const u16* __restrict__ w1e16,
    const float* __restrict__ qb2, const float* __restrict__ kb2, const float* __restrict__ vb2,
    const float* __restrict__ sbias, u8* __restrict__ wv) {
  __shared__ __align__(16) union {
    u16 H[16][520];       // fp16 H chunk (full K=512 per m)
    float S[16][8][8];    // attention scores (H dead by then)
  } s_u;
  __shared__ __align__(16) u8 s_QKV[3][16][272];  // e5m2 QKV
  __shared__ int s_src[16], s_dst[16];
  __shared__ __align__(16) float s_ea[16][4];
  __shared__ float s_bias[16][8];
  const int t = threadIdx.x;
  const int e0 = blockIdx.x * 16;
  if (t < 16) s_src[t] = eidx[e0 + t];
  else if (t < 32) s_dst[t - 16] = eidx[N_EDGES + e0 + t - 16];
  if (t < 64) {
    int i = t >> 2, c = t & 3;
    if (c < 3) s_ea[i][c] = eattr[(size_t)(e0 + i) * 7 + c];
  }
  if (t < 128) {
    int i = t >> 3, h = t & 7;
    s_bias[i][h] = sbias[(size_t)(e0 + i) * 8 + h];
  }
  __syncthreads();
  const int lane = t & 63, wave = t >> 6;
  const int lrow = lane & 15, quad = lane >> 4;
  const int wcol = wave * 64;
  const int ei = t >> 4, sub = t & 15;  // assembly mapping: 16 threads/edge, 32 cols each
  const float* b2s[3] = {qb2, kb2, vb2};
  const float a0 = s_ea[ei][0], a1 = s_ea[ei][1], a2 = s_ea[ei][2];
  h2 ea0h, ea1h, ea2h;
  ea0h[0] = ea0h[1] = (_Float16)a0;
  ea1h[0] = ea1h[1] = (_Float16)a1;
  ea2h[0] = ea2h[1] = (_Float16)a2;
  const size_t srcBase = (size_t)s_src[ei] * 3072 + sub * 32;
  const size_t dstBase = (size_t)s_dst[ei] * 3072 + 1536 + sub * 32;
#pragma unroll
  for (int m = 0; m < 3; ++m) {
    {  // ---- assemble H[16][512] fp16 ----
      const u8* rs = AB + srcBase + m * 512;
      const u8* rd = AB + dstBase + m * 512;
      alignas(16) unsigned sd[8], dd[8];
      *(uint4*)&sd[0] = *(const uint4*)rs;
      *(uint4*)&sd[4] = *(const uint4*)(rs + 16);
      *(uint4*)&dd[0] = *(const uint4*)rd;
      *(uint4*)&dd[4] = *(const uint4*)(rd + 16);
      const unsigned* w32 = (const unsigned*)(w1e16 + (size_t)m * 1536);
      const int cp0 = sub * 16;
      alignas(16) unsigned hout[16];
#pragma unroll
      for (int d = 0; d < 8; ++d) {
        int cp = cp0 + d * 2;
        h2 slo = e5lo(sd[d]) + e5lo(dd[d]);
        h2 shi = e5hi(sd[d]) + e5hi(dd[d]);
        slo += ea0h * __builtin_bit_cast(h2, w32[cp]);
        shi += ea0h * __builtin_bit_cast(h2, w32[cp + 1]);
        slo += ea1h * __builtin_bit_cast(h2, w32[256 + cp]);
        shi += ea1h * __builtin_bit_cast(h2, w32[256 + cp + 1]);
        slo += ea2h * __builtin_bit_cast(h2, w32[512 + cp]);
        shi += ea2h * __builtin_bit_cast(h2, w32[512 + cp + 1]);
        float g0 = gelu_s((float)slo[0]), g1 = gelu_s((float)slo[1]);
        float g2 = gelu_s((float)shi[0]), g3 = gelu_s((float)shi[1]);
        unsigned p0 = (unsigned)f2h(g0) | ((unsigned)f2h(g1) << 16);
        unsigned p1 = (unsigned)f2h(g2) | ((unsigned)f2h(g3) << 16);
        hout[d * 2] = p0;
        hout[d * 2 + 1] = p1;
      }
      uint4* hp = (uint4*)&s_u.H[ei][sub * 32];
      hp[0] = *(const uint4*)&hout[0];
      hp[1] = *(const uint4*)&hout[4];
      hp[2] = *(const uint4*)&hout[8];
      hp[3] = *(const uint4*)&hout[12];
    }
    __syncthreads();
    {  // ---- MFMA: [16,512] @ W2_m[512,256] ----
      f32x4 acc4[4];
      const f32x4 z = {0.f, 0.f, 0.f, 0.f};
#pragma unroll
      for (int j = 0; j < 4; ++j) acc4[j] = z;
      const u16* wbase = W2T + (size_t)(m * 256 + wcol) * 512;
#pragma unroll
      for (int k0 = 0; k0 < 512; k0 += 32) {
        v8h a = *(const v8h*)&s_u.H[lrow][k0 + quad * 8];
#pragma unroll
        for (int j = 0; j < 4; ++j) {
          v8h b = *(const v8h*)&wbase[(size_t)(j * 16 + lrow) * 512 + k0 + quad * 8];
          acc4[j] = __builtin_amdgcn_mfma_f32_16x16x32_f16(a, b, acc4[j], 0, 0, 0);
        }
      }
      const float* b2 = b2s[m];
#pragma unroll
      for (int j = 0; j < 4; ++j)
#pragma unroll
        for (int rg = 0; rg < 4; ++rg) {
          int row = quad * 4 + rg;
          int col = wcol + j * 16 + lrow;
          s_QKV[m][row][col] = f2e5m2(acc4[j][rg] + b2[col]);
        }
    }
    __syncthreads();
  }
  // ---- scores: S[i][h][g] = Q[i,h]·K[i,g]/sqrt(32) + bias[i,h] (packed fp16) ----
  if (t < 128) {
    int i = t >> 3, h = t & 7;
    alignas(16) unsigned qd[8];
    *(uint4*)&qd[0] = *(const uint4*)&s_QKV[0][i][h * 32];
    *(uint4*)&qd[4] = *(const uint4*)&s_QKV[0][i][h * 32 + 16];
    h2 qh[16];
#pragma unroll
    for (int d = 0; d < 8; ++d) { qh[d * 2] = e5lo(qd[d]); qh[d * 2 + 1] = e5hi(qd[d]); }
    float bias = s_bias[i][h];
    float sc[8];
#pragma unroll
    for (int g = 0; g < 8; ++g) {
      alignas(16) unsigned kd[8];
      *(uint4*)&kd[0] = *(const uint4*)&s_QKV[1][i][g * 32];
      *(uint4*)&kd[4] = *(const uint4*)&s_QKV[1][i][g * 32 + 16];
      h2 acc;
      acc[0] = acc[1] = (_Float16)0.f;
#pragma unroll
      for (int d = 0; d < 8; ++d) {
        acc += qh[d * 2] * e5lo(kd[d]);
        acc += qh[d * 2 + 1] * e5hi(kd[d]);
      }
      sc[g] = (float)acc[0] + (float)acc[1];
    }
#pragma unroll
    for (int g = 0; g < 8; ++g) s_u.S[i][h][g] = sc[g] * 0.17677669529663687f + bias;
  }
  __syncthreads();
  // ---- softmax over h (axis=1) per (i,g) ----
  if (t < 128) {
    int i = t >> 3, g = t & 7;
    float mx = -1e30f;
#pragma unroll
    for (int h = 0; h < 8; ++h) mx = fmaxf(mx, s_u.S[i][h][g]);
    float ev[8], ssum = 0.f;
#pragma unroll
    for (int h = 0; h < 8; ++h) {
      ev[h] = __expf(s_u.S[i][h][g] - mx);
      ssum += ev[h];
    }
    float inv = 1.0f / ssum;
#pragma unroll
    for (int h = 0; h < 8; ++h) s_u.S[i][h][g] = ev[h] * inv;
  }
  __syncthreads();
  // ---- wv[e][h*32..] = sum_g attn[h][g]*V[g][:] (packed fp16), e5m2 coalesced store ----
  if (t < 128) {
    int i = t >> 3, h = t & 7;
    h2 va[16];
#pragma unroll
    for (int u = 0; u < 16; ++u) va[u][0] = va[u][1] = (_Float16)0.f;
#pragma unroll
    for (int g = 0; g < 8; ++g) {
      float at = s_u.S[i][h][g];
      h2 at2;
      at2[0] = at2[1] = (_Float16)at;
      alignas(16) unsigned vd[8];
      *(uint4*)&vd[0] = *(const uint4*)&s_QKV[2][i][g * 32];
      *(uint4*)&vd[4] = *(const uint4*)&s_QKV[2][i][g * 32 + 16];
#pragma unroll
      for (int d = 0; d < 8; ++d) {
        va[d * 2] += at2 * e5lo(vd[d]);
        va[d * 2 + 1] += at2 * e5hi(vd[d]);
      }
    }
    alignas(16) unsigned od[8];
#pragma unroll
    for (int p = 0; p < 8; ++p) {
      unsigned a = __builtin_bit_cast(unsigned, va[p * 2]) + 0x00800080u;
      unsigned b = __builtin_bit_cast(unsigned, va[p * 2 + 1]) + 0x00800080u;
      od[p] = __builtin_amdgcn_perm(b, a, 0x07050301u);  // bytes [a1,a3,b1,b3]
    }
    u8* dp = wv + (size_t)(e0 + i) * 256 + h * 32;
    *(uint4*)dp = *(const uint4*)&od[0];
    *(uint4*)(dp + 16) = *(const uint4*)&od[4];
  }
}

// ---------------- node gather-mean + x1/X1cat build ----------------
__global__ __launch_bounds__(256) void node_gather(const unsigned* __restrict__ off,
                                                   const unsigned* __restrict__ cnt,
                                                   const unsigned* __restrict__ eid,
                                                   const u8* __restrict__ wv,
                                                   const float* __restrict__ x,
                                                   float* __restrict__ x1,
                                                   u16* __restrict__ X1cat) {
  int n = blockIdx.x * 4 + (threadIdx.x >> 6);
  int lane = threadIdx.x & 63;
  unsigned st = off[n], c = cnt[n];
  float a0 = 0.f, a1 = 0.f, a2 = 0.f, a3 = 0.f;
  for (unsigned j = 0; j < c; ++j) {
    unsigned e = eid[st + j];
    unsigned d = *(const unsigned*)(wv + (size_t)e * 256 + lane * 4);
    float f[4];
    dec4(d, f);
    a0 += f[0]; a1 += f[1]; a2 += f[2]; a3 += f[3];
  }
  float inv = 1.0f / fmaxf((float)c, 1.0f);
  float4 xv = *(const float4*)(x + (size_t)n * 256 + lane * 4);
  float4 x1v = {xv.x + a0 * inv, xv.y + a1 * inv, xv.z + a2 * inv, xv.w + a3 * inv};
  *(float4*)(x1 + (size_t)n * 256 + lane * 4) = x1v;
  ushort4 a, bq;
  a.x = f2h(x1v.x); a.y = f2h(x1v.y); a.z = f2h(x1v.z); a.w = f2h(x1v.w);
  bq.x = f2h(xv.x); bq.y = f2h(xv.y); bq.z = f2h(xv.z); bq.w = f2h(xv.w);
  *(ushort4*)(X1cat + (size_t)n * 512 + lane * 4) = a;
  *(ushort4*)(X1cat + (size_t)n * 512 + 256 + lane * 4) = bq;
}

extern "C" void kernel_launch(void* const* d_in, const int* in_sizes, int n_in,
                              void* d_out, int out_size, void* d_ws, size_t ws_size,
                              hipStream_t stream) {
  const float* x = (const float*)d_in[0];
  const int* eidx = (const int*)d_in[1];
  const float* eattr = (const float*)d_in[2];
  const float* qW1 = (const float*)d_in[3];
  const float* qb1 = (const float*)d_in[4];
  const float* qW2 = (const float*)d_in[5];
  const float* qb2 = (const float*)d_in[6];
  const float* kW1 = (const float*)d_in[7];
  const float* kb1 = (const float*)d_in[8];
  const float* kW2 = (const float*)d_in[9];
  const float* kb2 = (const float*)d_in[10];
  const float* vW1 = (const float*)d_in[11];
  const float* vb1 = (const float*)d_in[12];
  const float* vW2 = (const float*)d_in[13];
  const float* vb2 = (const float*)d_in[14];
  const float* sW1 = (const float*)d_in[15];
  const float* sb1 = (const float*)d_in[16];
  const float* sW2 = (const float*)d_in[17];
  const float* sb2 = (const float*)d_in[18];
  const float* fW1 = (const float*)d_in[19];
  const float* fb1 = (const float*)d_in[20];
  const float* fW2 = (const float*)d_in[21];
  const float* fb2 = (const float*)d_in[22];
  const float* lng = (const float*)d_in[23];
  const float* lnb = (const float*)d_in[24];
  const float* rW = (const float*)d_in[25];
  const float* rb = (const float*)d_in[26];

  const size_t N = N_NODES;
  char* ws = (char*)d_ws;
  size_t off_b = 0;
  auto alloc = [&](size_t bytes) {
    void* p = ws + off_b;
    off_b = (off_b + bytes + 255) & ~(size_t)255;
    return p;
  };
  u16* W1catT = (u16*)alloc((size_t)3072 * 256 * 2);
  u16* W2T = (u16*)alloc((size_t)768 * 512 * 2);
  u16* rWT = (u16*)alloc((size_t)256 * 512 * 2);
  u16* fW1T = (u16*)alloc((size_t)512 * 256 * 2);
  u16* fW2T = (u16*)alloc((size_t)256 * 512 * 2);
  u16* w1e16 = (u16*)alloc((size_t)9 * 512 * 2);
  float* b1cat = (float*)alloc((size_t)1536 * 4);
  u16* xn = (u16*)alloc(N * 256 * 2);
  unsigned* cnt = (unsigned*)alloc(N * 4);
  unsigned* offs = (unsigned*)alloc(N * 4);
  unsigned* woff = (unsigned*)alloc(N * 4);
  unsigned* eid = (unsigned*)alloc((size_t)N_EDGES * 4);
  float* sbias = (float*)alloc((size_t)N_EDGES * 8 * 4);
  u8* AB = (u8*)alloc(N * 3072);  // e5m2, 201 MB; node-stage tensors alias it
  u8* wv = (u8*)d_out;            // E*256 fp8 fits in d_out (N*256 floats)
  float* x1 = (float*)AB;                        // 64 MB
  u16* X1cat = (u16*)(AB + (size_t)67108864);    // 64 MB
  float* x2 = (float*)(AB + (size_t)134217728);  // 64 MB
  u16* xn2 = (u16*)AB;                           // 32 MB (x1 dead)
  u16* Hf = (u16*)(AB + (size_t)33554432);       // 64 MB (X1cat dead)

  hipMemsetAsync(cnt, 0, N * 4, stream);
  hist_kernel<<<N_EDGES / 256, 256, 0, stream>>>(eidx + N_EDGES, cnt);
  scan_kernel<<<1, 1024, 0, stream>>>(cnt, offs, woff);
  scatter_ids<<<N_EDGES / 256, 256, 0, stream>>>(eidx + N_EDGES, woff, eid);
  sbias_kernel<<<N_EDGES * 8 / 256, 256, 0, stream>>>(eattr, sW1, sb1, sW2, sb2, sbias);
  prep_w1catT<<<3072, 256, 0, stream>>>(W1catT, qW1, kW1, vW1);
  prep_w2T<<<768, 256, 0, stream>>>(W2T, qW2, kW2, vW2);
  prep_w1e16<<<9, 512, 0, stream>>>(w1e16, qW1, kW1, vW1);
  prep_b1cat<<<6, 256, 0, stream>>>(b1cat, qb1, kb1, vb1);
  transpose_cast<<<256, 256, 0, stream>>>(rWT, rW, 512, 256);
  transpose_cast<<<512, 256, 0, stream>>>(fW1T, fW1, 256, 512);
  transpose_cast<<<256, 256, 0, stream>>>(fW2T, fW2, 512, 256);

  ln_kernel<<<N_NODES / 4, 256, 0, stream>>>(x, lng, lnb, xn);
  gemm_bt<<<dim3(N_NODES / 128, 3072 / 128), 256, 0, stream>>>(xn, W1catT, 256, EpiAB{AB, b1cat});
  edge_kernel<<<N_EDGES / 16, 256, 0, stream>>>(eidx, eattr, AB, W2T, w1e16, qb2, kb2, vb2,
                                                sbias, wv);
  node_gather<<<N_NODES / 4, 256, 0, stream>>>(offs, cnt, eid, wv, x, x1, X1cat);
  gemm_bt<<<dim3(N_NODES / 128, 2), 256, 0, stream>>>(X1cat, rWT, 512, EpiX2{x2, x1, rb});
  ln_kernel<<<N_NODES / 4, 256, 0, stream>>>(x2, lng, lnb, xn2);
  gemm_bt<<<dim3(N_NODES / 128, 4), 256, 0, stream>>>(xn2, fW1T, 256, EpiHf{Hf, fb1});
  gemm_bt<<<dim3(N_NODES / 128, 2), 256, 0, stream>>>(Hf, fW2T, 512, EpiOut{(float*)d_out, fb2, x2});
}

// Round 5
// 1983.275 us; speedup vs baseline: 1.3535x; 1.3535x over previous
//
#include <hip/hip_runtime.h>

#define N_NODES 65536
#define N_EDGES 262144
#define EBATCH 32768  // edges per batch (8 batches) -> qkv buffer 25 MB

typedef unsigned short u16;
typedef unsigned char u8;
typedef float f32x4 __attribute__((ext_vector_type(4)));
typedef _Float16 h2 __attribute__((ext_vector_type(2)));
typedef _Float16 v8h __attribute__((ext_vector_type(8)));

__device__ __forceinline__ u16 f2h(float f) {
  return __builtin_bit_cast(u16, (_Float16)f);
}
// 8-bit e5m2 == top byte of fp16 with RNE rounding.
__device__ __forceinline__ u8 f2e5m2(float f) {
  _Float16 h = (_Float16)f;
  u16 hb = __builtin_bit_cast(u16, h);
  hb = (u16)(hb + 0x7F + ((hb >> 8) & 1));
  return (u8)(hb >> 8);
}
// decode dword = 4 e5m2 bytes -> 4 floats (node_gather)
__device__ __forceinline__ void dec4(unsigned d, float* o) {
  o[0] = (float)__builtin_bit_cast(_Float16, (u16)((d << 8) & 0xFF00u));
  o[1] = (float)__builtin_bit_cast(_Float16, (u16)(d & 0xFF00u));
  o[2] = (float)__builtin_bit_cast(_Float16, (u16)((d >> 8) & 0xFF00u));
  o[3] = (float)__builtin_bit_cast(_Float16, (u16)((d >> 16) & 0xFF00u));
}
// e5m2 bytes (b0,b1) of dword -> fp16 pair via one v_perm
__device__ __forceinline__ h2 e5lo(unsigned d) {
  return __builtin_bit_cast(h2, __builtin_amdgcn_perm(d, 0u, 0x05000400u));
}
__device__ __forceinline__ h2 e5hi(unsigned d) {
  return __builtin_bit_cast(h2, __builtin_amdgcn_perm(d, 0u, 0x07000600u));
}
// sigmoid-form gelu: x - x/(1+exp(1.702x)); ~6 VALU ops
__device__ __forceinline__ float gelu_s(float x) {
  float e = __expf(1.702f * x);
  return x - __fdividef(x, e + 1.0f);
}
// tanh-form gelu (node f-MLP epilogue)
__device__ __forceinline__ float gelu_f(float x) {
  float y = 1.5957691216057308f * (x + 0.044715f * x * x * x);
  float e = __expf(y);
  return x - __fdividef(x, e + 1.0f);
}

// ---------------- LayerNorm -> fp16 ----------------
__global__ __launch_bounds__(256) void ln_kernel(const float* __restrict__ x,
                                                 const float* __restrict__ g,
                                                 const float* __restrict__ b,
                                                 u16* __restrict__ out) {
  int row = blockIdx.x * 4 + (threadIdx.x >> 6);
  int lane = threadIdx.x & 63;
  float4 v = ((const float4*)(x + (size_t)row * 256))[lane];
  float s = v.x + v.y + v.z + v.w;
  float s2 = v.x * v.x + v.y * v.y + v.z * v.z + v.w * v.w;
#pragma unroll
  for (int off = 1; off < 64; off <<= 1) {
    s += __shfl_xor(s, off, 64);
    s2 += __shfl_xor(s2, off, 64);
  }
  float mean = s * (1.0f / 256.0f);
  float var = s2 * (1.0f / 256.0f) - mean * mean;
  float rs = rsqrtf(var + 1e-5f);
  float4 gv = ((const float4*)g)[lane];
  float4 bv = ((const float4*)b)[lane];
  ushort4 o;
  o.x = f2h((v.x - mean) * rs * gv.x + bv.x);
  o.y = f2h((v.y - mean) * rs * gv.y + bv.y);
  o.z = f2h((v.z - mean) * rs * gv.z + bv.z);
  o.w = f2h((v.w - mean) * rs * gv.w + bv.w);
  *(ushort4*)(out + (size_t)row * 256 + lane * 4) = o;
}

// ---------------- generic fp16 GEMM: C[m,n] = sum_k A[m,k] * BT[n,k] ----------------
template <typename Epi>
__global__ __launch_bounds__(256) void gemm_bt(const u16* __restrict__ A,
                                               const u16* __restrict__ BT,
                                               int K, Epi epi) {
  __shared__ __align__(16) u16 sA[128 * 48];
  __shared__ __align__(16) u16 sB[128 * 48];
  const int tm = blockIdx.x * 128, tn = blockIdx.y * 128;
  const int t = threadIdx.x;
  const int wave = t >> 6, lane = t & 63;
  const int lrow = lane & 15, quad = lane >> 4;
  const int wrow = (wave & 1) * 64, wcol = (wave >> 1) * 64;
  const int r = t >> 2, c = (t & 3) << 3;
  f32x4 acc[4][4];
  const f32x4 z = {0.f, 0.f, 0.f, 0.f};
#pragma unroll
  for (int i = 0; i < 4; ++i)
#pragma unroll
    for (int j = 0; j < 4; ++j) acc[i][j] = z;
  for (int k0 = 0; k0 < K; k0 += 32) {
    *(uint4*)&sA[r * 48 + c] = *(const uint4*)&A[(size_t)(tm + r) * K + k0 + c];
    *(uint4*)&sA[(r + 64) * 48 + c] = *(const uint4*)&A[(size_t)(tm + r + 64) * K + k0 + c];
    *(uint4*)&sB[r * 48 + c] = *(const uint4*)&BT[(size_t)(tn + r) * K + k0 + c];
    *(uint4*)&sB[(r + 64) * 48 + c] = *(const uint4*)&BT[(size_t)(tn + r + 64) * K + k0 + c];
    __syncthreads();
    v8h af[4], bfv[4];
#pragma unroll
    for (int i = 0; i < 4; ++i) af[i] = *(const v8h*)&sA[(wrow + i * 16 + lrow) * 48 + quad * 8];
#pragma unroll
    for (int j = 0; j < 4; ++j) bfv[j] = *(const v8h*)&sB[(wcol + j * 16 + lrow) * 48 + quad * 8];
#pragma unroll
    for (int i = 0; i < 4; ++i)
#pragma unroll
      for (int j = 0; j < 4; ++j)
        acc[i][j] = __builtin_amdgcn_mfma_f32_16x16x32_f16(af[i], bfv[j], acc[i][j], 0, 0, 0);
    __syncthreads();
  }
#pragma unroll
  for (int i = 0; i < 4; ++i)
#pragma unroll
    for (int j = 0; j < 4; ++j)
#pragma unroll
      for (int rg = 0; rg < 4; ++rg)
        epi(tm + wrow + i * 16 + quad * 4 + rg, tn + wcol + j * 16 + lrow, acc[i][j][rg]);
}

struct EpiAB {
  u8* out;
  const float* b1cat;
  __device__ void operator()(int m, int n, float v) const {
    if (n < 1536) v += b1cat[n];  // fold b1 into src half
    out[(size_t)m * 3072 + n] = f2e5m2(v);
  }
};
struct EpiX2 {
  float* x2;
  const float* x1;
  const float* rb;
  __device__ void operator()(int m, int n, float v) const {
    x2[(size_t)m * 256 + n] = v + rb[n] + x1[(size_t)m * 256 + n];
  }
};
struct EpiHf {
  u16* hf;
  const float* b1;
  __device__ void operator()(int m, int n, float v) const {
    hf[(size_t)m * 512 + n] = f2h(gelu_f(v + b1[n]));
  }
};
struct EpiOut {
  float* out;
  const float* b2;
  const float* x2;
  __device__ void operator()(int m, int n, float v) const {
    out[(size_t)m * 256 + n] = v + b2[n] + x2[(size_t)m * 256 + n];
  }
};

// ---------------- weight repacks ----------------
__global__ void prep_w1catT(u16* __restrict__ out, const float* __restrict__ qW1,
                            const float* __restrict__ kW1, const float* __restrict__ vW1) {
  int cIdx = blockIdx.x;
  int rIdx = threadIdx.x;
  int sec = cIdx >> 9;
  int h = cIdx & 511;
  int mlp = sec % 3;
  const float* W1 = (mlp == 0) ? qW1 : (mlp == 1) ? kW1 : vW1;
  int rowoff = (sec < 3) ? 0 : 256;
  out[(size_t)cIdx * 256 + rIdx] = f2h(W1[(size_t)(rowoff + rIdx) * 512 + h]);
}
__global__ void prep_w2T(u16* __restrict__ out, const float* __restrict__ qW2,
                         const float* __restrict__ kW2, const float* __restrict__ vW2) {
  int row = blockIdx.x;
  int m = row >> 8, n = row & 255;
  const float* W2 = (m == 0) ? qW2 : (m == 1) ? kW2 : vW2;
  for (int k = threadIdx.x; k < 512; k += 256)
    out[(size_t)row * 512 + k] = f2h(W2[(size_t)k * 256 + n]);
}
__global__ void transpose_cast(u16* __restrict__ out, const float* __restrict__ in, int K, int Nn) {
  int n = blockIdx.x;
  for (int k = threadIdx.x; k < K; k += blockDim.x)
    out[(size_t)n * K + k] = f2h(in[(size_t)k * Nn + n]);
}
__global__ void prep_w1e16(u16* __restrict__ out, const float* __restrict__ qW1,
                           const float* __restrict__ kW1, const float* __restrict__ vW1) {
  int b = blockIdx.x;  // m*3 + r
  int m = b / 3, r = b % 3;
  const float* W1 = (m == 0) ? qW1 : (m == 1) ? kW1 : vW1;
  out[(size_t)b * 512 + threadIdx.x] = f2h(W1[(size_t)(512 + r) * 512 + threadIdx.x]);
}
__global__ void prep_b1cat(float* __restrict__ out, const float* __restrict__ qb1,
                           const float* __restrict__ kb1, const float* __restrict__ vb1) {
  int idx = blockIdx.x * 256 + threadIdx.x;  // 1536
  const float* b = (idx < 512) ? qb1 : (idx < 1024) ? kb1 : vb1;
  out[idx] = b[idx & 511];
}

// ---------------- CSR build ----------------
__global__ __launch_bounds__(256) void hist_kernel(const int* __restrict__ dst,
                                                   unsigned* __restrict__ cnt) {
  int e = blockIdx.x * 256 + threadIdx.x;
  atomicAdd(&cnt[dst[e]], 1u);
}
__global__ __launch_bounds__(1024) void scan_kernel(const unsigned* __restrict__ cnt,
                                                    unsigned* __restrict__ off,
                                                    unsigned* __restrict__ woff) {
  __shared__ unsigned s_part[1024];
  int t = threadIdx.x;
  unsigned local[64];
  unsigned run = 0;
  const uint4* cp = (const uint4*)(cnt + t * 64);
#pragma unroll
  for (int j = 0; j < 16; ++j) {
    uint4 v = cp[j];
    local[j * 4 + 0] = v.x; local[j * 4 + 1] = v.y;
    local[j * 4 + 2] = v.z; local[j * 4 + 3] = v.w;
  }
#pragma unroll
  for (int j = 0; j < 64; ++j) { unsigned c = local[j]; local[j] = run; run += c; }
  s_part[t] = run;
  __syncthreads();
  for (int d = 1; d < 1024; d <<= 1) {
    unsigned v = (t >= d) ? s_part[t - d] : 0u;
    __syncthreads();
    s_part[t] += v;
    __syncthreads();
  }
  unsigned base = (t == 0) ? 0u : s_part[t - 1];
  for (int j = 0; j < 64; ++j) {
    unsigned o = base + local[j];
    off[t * 64 + j] = o;
    woff[t * 64 + j] = o;
  }
}
__global__ __launch_bounds__(256) void scatter_ids(const int* __restrict__ dst,
                                                   unsigned* __restrict__ woff,
                                                   unsigned* __restrict__ eid) {
  int e = blockIdx.x * 256 + threadIdx.x;
  unsigned pos = atomicAdd(&woff[dst[e]], 1u);
  eid[pos] = (unsigned)e;
}

// ---------------- QKV GEMM: 64-edge x 256-col tiles, one m per blockIdx.y ----------------
// H[64,512] assembled on the fly (gather AB-fp8 + edge terms, gelu, fp16) in K=128 chunks.
// Writes qkv[local_e][m*256+c] as e5m2.
__global__ __launch_bounds__(256) void qkv_gemm(
    const int* __restrict__ eidx, const float* __restrict__ eattr,
    const u8* __restrict__ AB, const u16* __restrict__ W2T, const u16* __restrict__ w1e16,
    const float* __restrict__ qb2, const float* __restrict__ kb2, const float* __restrict__ vb2,
    int ebase, u8* __restrict__ qkv) {
  __shared__ __align__(16) u16 sH[64][136];  // K-chunk 128 fp16, stride 272B
  __shared__ int s_src[64], s_dst[64];
  __shared__ __align__(16) float s_ea[64][4];
  const int m = blockIdx.y;
  const int t = threadIdx.x;
  const int e0 = ebase + blockIdx.x * 64;  // global edge base
  if (t < 64) {
    s_src[t] = eidx[e0 + t];
    s_dst[t] = eidx[N_EDGES + e0 + t];
  } else if (t >= 128 && t < 192) {
    int i = t - 128;
    const float* ea = eattr + (size_t)(e0 + i) * 7;
    s_ea[i][0] = ea[0]; s_ea[i][1] = ea[1]; s_ea[i][2] = ea[2];
  }
  __syncthreads();
  const int i = t & 63, seg = t >> 6;
  const int lane = t & 63, wave = t >> 6;
  const int lrow = lane & 15, quad = lane >> 4;
  const int wrow = (wave & 1) * 32, wcol = (wave >> 1) * 128;
  h2 ea0h, ea1h, ea2h;
  ea0h[0] = ea0h[1] = (_Float16)s_ea[i][0];
  ea1h[0] = ea1h[1] = (_Float16)s_ea[i][1];
  ea2h[0] = ea2h[1] = (_Float16)s_ea[i][2];
  const u8* rsB = AB + (size_t)s_src[i] * 3072 + m * 512 + seg * 32;
  const u8* rdB = AB + (size_t)s_dst[i] * 3072 + 1536 + m * 512 + seg * 32;
  const unsigned* w32 = (const unsigned*)(w1e16 + (size_t)m * 1536);
  f32x4 acc[2][8];
  const f32x4 z = {0.f, 0.f, 0.f, 0.f};
#pragma unroll
  for (int i2 = 0; i2 < 2; ++i2)
#pragma unroll
    for (int j = 0; j < 8; ++j) acc[i2][j] = z;
  for (int k0 = 0; k0 < 512; k0 += 128) {
    {  // assemble 32 cols per thread: edge i, cols [k0+seg*32, +32)
      alignas(16) unsigned sd[8], dd[8];
      *(uint4*)&sd[0] = *(const uint4*)(rsB + k0);
      *(uint4*)&sd[4] = *(const uint4*)(rsB + k0 + 16);
      *(uint4*)&dd[0] = *(const uint4*)(rdB + k0);
      *(uint4*)&dd[4] = *(const uint4*)(rdB + k0 + 16);
      const int cp0 = (k0 + seg * 32) >> 1;
      alignas(16) unsigned hout[16];
#pragma unroll
      for (int d = 0; d < 8; ++d) {
        int cp = cp0 + d * 2;
        h2 slo = e5lo(sd[d]) + e5lo(dd[d]);
        h2 shi = e5hi(sd[d]) + e5hi(dd[d]);
        slo += ea0h * __builtin_bit_cast(h2, w32[cp]);
        shi += ea0h * __builtin_bit_cast(h2, w32[cp + 1]);
        slo += ea1h * __builtin_bit_cast(h2, w32[256 + cp]);
        shi += ea1h * __builtin_bit_cast(h2, w32[256 + cp + 1]);
        slo += ea2h * __builtin_bit_cast(h2, w32[512 + cp]);
        shi += ea2h * __builtin_bit_cast(h2, w32[512 + cp + 1]);
        float g0 = gelu_s((float)slo[0]), g1 = gelu_s((float)slo[1]);
        float g2 = gelu_s((float)shi[0]), g3 = gelu_s((float)shi[1]);
        hout[d * 2] = (unsigned)f2h(g0) | ((unsigned)f2h(g1) << 16);
        hout[d * 2 + 1] = (unsigned)f2h(g2) | ((unsigned)f2h(g3) << 16);
      }
      uint4* hp = (uint4*)&sH[i][seg * 32];
      hp[0] = *(const uint4*)&hout[0];
      hp[1] = *(const uint4*)&hout[4];
      hp[2] = *(const uint4*)&hout[8];
      hp[3] = *(const uint4*)&hout[12];
    }
    __syncthreads();
#pragma unroll
    for (int ks = 0; ks < 4; ++ks) {
      int kk = ks * 32;
      v8h a0 = *(const v8h*)&sH[wrow + lrow][kk + quad * 8];
      v8h a1 = *(const v8h*)&sH[wrow + 16 + lrow][kk + quad * 8];
#pragma unroll
      for (int j = 0; j < 8; ++j) {
        v8h b = *(const v8h*)&W2T[(size_t)(m * 256 + wcol + j * 16 + lrow) * 512 + k0 + kk + quad * 8];
        acc[0][j] = __builtin_amdgcn_mfma_f32_16x16x32_f16(a0, b, acc[0][j], 0, 0, 0);
        acc[1][j] = __builtin_amdgcn_mfma_f32_16x16x32_f16(a1, b, acc[1][j], 0, 0, 0);
      }
    }
    __syncthreads();
  }
  // epilogue: +b2, e5m2-encode into LDS (reuse sH as byte buf, stride 272), coalesced copy out
  const float* b2 = (m == 0) ? qb2 : (m == 1) ? kb2 : vb2;
  u8* sb = (u8*)sH;
#pragma unroll
  for (int i2 = 0; i2 < 2; ++i2)
#pragma unroll
    for (int j = 0; j < 8; ++j)
#pragma unroll
      for (int rg = 0; rg < 4; ++rg) {
        int row = wrow + i2 * 16 + quad * 4 + rg;
        int col = wcol + j * 16 + lrow;
        sb[row * 272 + col] = f2e5m2(acc[i2][j][rg] + b2[col]);
      }
  __syncthreads();
  {
    int ir = t >> 2, sg = t & 3;
    const u8* srcp = &sb[ir * 272 + sg * 64];
    uint4* dstp = (uint4*)(qkv + (size_t)(blockIdx.x * 64 + ir) * 768 + m * 256 + sg * 64);
    dstp[0] = *(const uint4*)srcp;
    dstp[1] = *(const uint4*)(srcp + 16);
    dstp[2] = *(const uint4*)(srcp + 32);
    dstp[3] = *(const uint4*)(srcp + 48);
  }
}

// ---------------- attention: 32 edges/block, 256 threads, 3 barriers ----------------
__global__ __launch_bounds__(256) void attn_kernel(
    const u8* __restrict__ qkv, const float* __restrict__ eattr,
    const float* __restrict__ sW1, const float* __restrict__ sb1,
    const float* __restrict__ sW2, const float* __restrict__ sb2,
    int ebase, u8* __restrict__ wv) {
  __shared__ __align__(16) u8 sQ[32][784];  // [edge][768 qkv bytes], stride 784
  __shared__ float sS[32][8][8];
  const int t = threadIdx.x;
  const int el0 = blockIdx.x * 32;  // batch-local edge base
  const int i = t >> 3, h = t & 7;
  {  // stage qkv: 6 x uint4 per thread, coalesced
    const uint4* g = (const uint4*)(qkv + (size_t)(el0 + i) * 768);
    uint4* l = (uint4*)&sQ[i][0];
#pragma unroll
    for (int j = 0; j < 6; ++j) l[h + j * 8] = g[h + j * 8];
  }
  // s-MLP bias (overlaps staging latency; global-only reads)
  float bias;
  {
    const float* ea = eattr + (size_t)(ebase + el0 + i) * 7;
    float a0 = ea[3], a1 = ea[4], a2 = ea[5], a3 = ea[6];
    float acc = sb2[h];
#pragma unroll 4
    for (int j = 0; j < 64; ++j) {
      float zz = fmaxf(a0 * sW1[j] + a1 * sW1[64 + j] + a2 * sW1[128 + j] + a3 * sW1[192 + j] + sb1[j], 0.f);
      acc += zz * sW2[j * 8 + h];
    }
    bias = acc;
  }
  __syncthreads();
  {  // scores S[i][h][g] = Q·K/sqrt(32) + bias (packed fp16)
    alignas(16) unsigned qd[8];
    *(uint4*)&qd[0] = *(const uint4*)&sQ[i][h * 32];
    *(uint4*)&qd[4] = *(const uint4*)&sQ[i][h * 32 + 16];
    h2 qh[16];
#pragma unroll
    for (int d = 0; d < 8; ++d) { qh[d * 2] = e5lo(qd[d]); qh[d * 2 + 1] = e5hi(qd[d]); }
    float sc[8];
#pragma unroll
    for (int g = 0; g < 8; ++g) {
      alignas(16) unsigned kd[8];
      *(uint4*)&kd[0] = *(const uint4*)&sQ[i][256 + g * 32];
      *(uint4*)&kd[4] = *(const uint4*)&sQ[i][256 + g * 32 + 16];
      h2 acc;
      acc[0] = acc[1] = (_Float16)0.f;
#pragma unroll
      for (int d = 0; d < 8; ++d) {
        acc += qh[d * 2] * e5lo(kd[d]);
        acc += qh[d * 2 + 1] * e5hi(kd[d]);
      }
      sc[g] = (float)acc[0] + (float)acc[1];
    }
#pragma unroll
    for (int g = 0; g < 8; ++g) sS[i][h][g] = sc[g] * 0.17677669529663687f + bias;
  }
  __syncthreads();
  {  // softmax over h (axis=1) per (i,g): here thread handles g = h index
    int g = h;
    float mx = -1e30f;
#pragma unroll
    for (int hh = 0; hh < 8; ++hh) mx = fmaxf(mx, sS[i][hh][g]);
    float ev[8], ssum = 0.f;
#pragma unroll
    for (int hh = 0; hh < 8; ++hh) {
      ev[hh] = __expf(sS[i][hh][g] - mx);
      ssum += ev[hh];
    }
    float inv = 1.0f / ssum;
#pragma unroll
    for (int hh = 0; hh < 8; ++hh) sS[i][hh][g] = ev[hh] * inv;
  }
  __syncthreads();
  {  // wv[e][h*32..] = sum_g attn[h][g]*V[g][:]
    h2 va[16];
#pragma unroll
    for (int u = 0; u < 16; ++u) va[u][0] = va[u][1] = (_Float16)0.f;
#pragma unroll
    for (int g = 0; g < 8; ++g) {
      float at = sS[i][h][g];
      h2 at2;
      at2[0] = at2[1] = (_Float16)at;
      alignas(16) unsigned vd[8];
      *(uint4*)&vd[0] = *(const uint4*)&sQ[i][512 + g * 32];
      *(uint4*)&vd[4] = *(const uint4*)&sQ[i][512 + g * 32 + 16];
#pragma unroll
      for (int d = 0; d < 8; ++d) {
        va[d * 2] += at2 * e5lo(vd[d]);
        va[d * 2 + 1] += at2 * e5hi(vd[d]);
      }
    }
    alignas(16) unsigned od[8];
#pragma unroll
    for (int p = 0; p < 8; ++p) {
      unsigned a = __builtin_bit_cast(unsigned, va[p * 2]) + 0x00800080u;
      unsigned b = __builtin_bit_cast(unsigned, va[p * 2 + 1]) + 0x00800080u;
      od[p] = __builtin_amdgcn_perm(b, a, 0x07050301u);
    }
    u8* dp = wv + (size_t)(ebase + el0 + i) * 256 + h * 32;
    *(uint4*)dp = *(const uint4*)&od[0];
    *(uint4*)(dp + 16) = *(const uint4*)&od[4];
  }
}

// ---------------- node gather-mean + x1/X1cat build ----------------
__global__ __launch_bounds__(256) void node_gather(const unsigned* __restrict__ off,
                                                   const unsigned* __restrict__ cnt,
                                                   const unsigned* __restrict__ eid,
                                                   const u8* __restrict__ wv,
                                                   const float* __restrict__ x,
                                                   float* __restrict__ x1,
                                                   u16* __restrict__ X1cat) {
  int n = blockIdx.x * 4 + (threadIdx.x >> 6);
  int lane = threadIdx.x & 63;
  unsigned st = off[n], c = cnt[n];
  float a0 = 0.f, a1 = 0.f, a2 = 0.f, a3 = 0.f;
  for (unsigned j = 0; j < c; ++j) {
    unsigned e = eid[st + j];
    unsigned d = *(const unsigned*)(wv + (size_t)e * 256 + lane * 4);
    float f[4];
    dec4(d, f);
    a0 += f[0]; a1 += f[1]; a2 += f[2]; a3 += f[3];
  }
  float inv = 1.0f / fmaxf((float)c, 1.0f);
  float4 xv = *(const float4*)(x + (size_t)n * 256 + lane * 4);
  float4 x1v = {xv.x + a0 * inv, xv.y + a1 * inv, xv.z + a2 * inv, xv.w + a3 * inv};
  *(float4*)(x1 + (size_t)n * 256 + lane * 4) = x1v;
  ushort4 a, bq;
  a.x = f2h(x1v.x); a.y = f2h(x1v.y); a.z = f2h(x1v.z); a.w = f2h(x1v.w);
  bq.x = f2h(xv.x); bq.y = f2h(xv.y); bq.z = f2h(xv.z); bq.w = f2h(xv.w);
  *(ushort4*)(X1cat + (size_t)n * 512 + lane * 4) = a;
  *(ushort4*)(X1cat + (size_t)n * 512 + 256 + lane * 4) = bq;
}

extern "C" void kernel_launch(void* const* d_in, const int* in_sizes, int n_in,
                              void* d_out, int out_size, void* d_ws, size_t ws_size,
                              hipStream_t stream) {
  const float* x = (const float*)d_in[0];
  const int* eidx = (const int*)d_in[1];
  const float* eattr = (const float*)d_in[2];
  const float* qW1 = (const float*)d_in[3];
  const float* qb1 = (const float*)d_in[4];
  const float* qW2 = (const float*)d_in[5];
  const float* qb2 = (const float*)d_in[6];
  const float* kW1 = (const float*)d_in[7];
  const float* kb1 = (const float*)d_in[8];
  const float* kW2 = (const float*)d_in[9];
  const float* kb2 = (const float*)d_in[10];
  const float* vW1 = (const float*)d_in[11];
  const float* vb1 = (const float*)d_in[12];
  const float* vW2 = (const float*)d_in[13];
  const float* vb2 = (const float*)d_in[14];
  const float* sW1 = (const float*)d_in[15];
  const float* sb1 = (const float*)d_in[16];
  const float* sW2 = (const float*)d_in[17];
  const float* sb2 = (const float*)d_in[18];
  const float* fW1 = (const float*)d_in[19];
  const float* fb1 = (const float*)d_in[20];
  const float* fW2 = (const float*)d_in[21];
  const float* fb2 = (const float*)d_in[22];
  const float* lng = (const float*)d_in[23];
  const float* lnb = (const float*)d_in[24];
  const float* rW = (const float*)d_in[25];
  const float* rb = (const float*)d_in[26];

  const size_t N = N_NODES;
  char* ws = (char*)d_ws;
  size_t off_b = 0;
  auto alloc = [&](size_t bytes) {
    void* p = ws + off_b;
    off_b = (off_b + bytes + 255) & ~(size_t)255;
    return p;
  };
  u16* W1catT = (u16*)alloc((size_t)3072 * 256 * 2);
  u16* W2T = (u16*)alloc((size_t)768 * 512 * 2);
  u16* rWT = (u16*)alloc((size_t)256 * 512 * 2);
  u16* fW1T = (u16*)alloc((size_t)512 * 256 * 2);
  u16* fW2T = (u16*)alloc((size_t)256 * 512 * 2);
  u16* w1e16 = (u16*)alloc((size_t)9 * 512 * 2);
  float* b1cat = (float*)alloc((size_t)1536 * 4);
  unsigned* cnt = (unsigned*)alloc(N * 4);
  unsigned* offs = (unsigned*)alloc(N * 4);
  unsigned* woff = (unsigned*)alloc(N * 4);
  unsigned* eid = (unsigned*)alloc((size_t)N_EDGES * 4);
  u8* qkv = (u8*)alloc((size_t)EBATCH * 768);  // 25.2 MB batch QKV
  u8* AB = (u8*)alloc(N * 3072);               // e5m2, 201 MB; node-stage aliases below
  // xn (fp16 LN output, 33.5 MB) and wv (fp8 per-edge, 67 MB) both live in d_out;
  // xn is dead before the first attn_kernel writes wv.
  u16* xn = (u16*)d_out;
  u8* wv = (u8*)d_out;
  float* x1 = (float*)AB;                        // 64 MB
  u16* X1cat = (u16*)(AB + (size_t)67108864);    // 64 MB
  float* x2 = (float*)(AB + (size_t)134217728);  // 64 MB
  u16* xn2 = (u16*)AB;                           // 32 MB (x1 dead)
  u16* Hf = (u16*)(AB + (size_t)33554432);       // 64 MB (X1cat dead)

  hipMemsetAsync(cnt, 0, N * 4, stream);
  hist_kernel<<<N_EDGES / 256, 256, 0, stream>>>(eidx + N_EDGES, cnt);
  scan_kernel<<<1, 1024, 0, stream>>>(cnt, offs, woff);
  scatter_ids<<<N_EDGES / 256, 256, 0, stream>>>(eidx + N_EDGES, woff, eid);
  prep_w1catT<<<3072, 256, 0, stream>>>(W1catT, qW1, kW1, vW1);
  prep_w2T<<<768, 256, 0, stream>>>(W2T, qW2, kW2, vW2);
  prep_w1e16<<<9, 512, 0, stream>>>(w1e16, qW1, kW1, vW1);
  prep_b1cat<<<6, 256, 0, stream>>>(b1cat, qb1, kb1, vb1);
  transpose_cast<<<256, 256, 0, stream>>>(rWT, rW, 512, 256);
  transpose_cast<<<512, 256, 0, stream>>>(fW1T, fW1, 256, 512);
  transpose_cast<<<256, 256, 0, stream>>>(fW2T, fW2, 512, 256);

  ln_kernel<<<N_NODES / 4, 256, 0, stream>>>(x, lng, lnb, xn);
  gemm_bt<<<dim3(N_NODES / 128, 3072 / 128), 256, 0, stream>>>(xn, W1catT, 256, EpiAB{AB, b1cat});
  for (int b = 0; b < N_EDGES / EBATCH; ++b) {
    int ebase = b * EBATCH;
    qkv_gemm<<<dim3(EBATCH / 64, 3), 256, 0, stream>>>(eidx, eattr, AB, W2T, w1e16,
                                                       qb2, kb2, vb2, ebase, qkv);
    attn_kernel<<<EBATCH / 32, 256, 0, stream>>>(qkv, eattr, sW1, sb1, sW2, sb2, ebase, wv);
  }
  node_gather<<<N_NODES / 4, 256, 0, stream>>>(offs, cnt, eid, wv, x, x1, X1cat);
  gemm_bt<<<dim3(N_NODES / 128, 2), 256, 0, stream>>>(X1cat, rWT, 512, EpiX2{x2, x1, rb});
  ln_kernel<<<N_NODES / 4, 256, 0, stream>>>(x2, lng, lnb, xn2);
  gemm_bt<<<dim3(N_NODES / 128, 4), 256, 0, stream>>>(xn2, fW1T, 256, EpiHf{Hf, fb1});
  gemm_bt<<<dim3(N_NODES / 128, 2), 256, 0, stream>>>(Hf, fW2T, 512, EpiOut{(float*)d_out, fb2, x2});
}